// Round 12
// baseline (85.301 us; speedup 1.0000x reference)
//
#include <hip/hip_runtime.h>
#include <math.h>

// ============================================================================
// R12 = R11 (fused, wave-private, 2 queries/wave) + SoA scan coordinates.
// R9 calibration: in-pipeline memory time ~ 2x quiet, quiet ~ serial window
// drains. AoS windows carry 3x the cache lines of SoA ones; R11 was the
// first structure lean enough for that term to show. Emit keeps AoS (random
// 12 B gathers). soa transpose: 0.4 MB into d_ws, ~1.3 us.
// ============================================================================

// Problem constants (fixed by setup_inputs): B=4, N=8192, P=2048, NSAMPLE=32.
constexpr int Bc  = 4;
constexpr int Nc  = 8192;
constexpr int Pc  = 2048;
constexpr int Sc  = 32;
constexpr int CHc = 34;      // 2 invariance + 4*8 quat channels
constexpr int NQ  = Bc * Pc; // 8192 queries
constexpr int BN  = Bc * Nc; // 32768 points; ws = x[BN] | y[BN] | z[BN]

// JAX >= 0.4.36 defaults jax_threefry_partitionable=True (validated in R1).
#define THREEFRY_PARTITIONABLE 1

#define FMUL __fmul_rn
#define FADD __fadd_rn
#define FSUB __fsub_rn

__device__ __forceinline__ unsigned tf_rotl(unsigned x, int r) {
  return (x << r) | (x >> (32 - r));
}

// Threefry-2x32, 20 rounds, key = (0, 42)  [jax.random.key(42)]
__device__ __forceinline__ void threefry2x32_k42(unsigned& x0, unsigned& x1) {
  const unsigned ks0 = 0u, ks1 = 42u, ks2 = 0u ^ 42u ^ 0x1BD11BDAu;
  x0 += ks0; x1 += ks1;
#define TF_ROUND(r) { x0 += x1; x1 = tf_rotl(x1, (r)); x1 ^= x0; }
  TF_ROUND(13) TF_ROUND(15) TF_ROUND(26) TF_ROUND(6)
  x0 += ks1; x1 += ks2 + 1u;
  TF_ROUND(17) TF_ROUND(29) TF_ROUND(16) TF_ROUND(24)
  x0 += ks2; x1 += ks0 + 2u;
  TF_ROUND(13) TF_ROUND(15) TF_ROUND(26) TF_ROUND(6)
  x0 += ks0; x1 += ks1 + 3u;
  TF_ROUND(17) TF_ROUND(29) TF_ROUND(16) TF_ROUND(24)
  x0 += ks1; x1 += ks2 + 4u;
  TF_ROUND(13) TF_ROUND(15) TF_ROUND(26) TF_ROUND(6)
  x0 += ks2; x1 += ks0 + 5u;
#undef TF_ROUND
}

// Bit-exact replica of (jax.random.uniform(key(42), (B,1,P,S)) - 0.5) * 2*pi
// at flat counter n. Total count = B*1*P*S = 262144.
__device__ __forceinline__ float jax_rnd_angle(unsigned n) {
#if THREEFRY_PARTITIONABLE
  unsigned x0 = 0u, x1 = n;          // hi32(n)=0, lo32(n)=n
  threefry2x32_k42(x0, x1);
  unsigned bits = x0 ^ x1;
#else
  const unsigned half = (unsigned)(Bc * Pc * Sc) / 2u;  // 131072
  unsigned x0, x1;
  bool second = (n >= half);
  if (second) { x0 = n - half; x1 = n; } else { x0 = n; x1 = n + half; }
  threefry2x32_k42(x0, x1);
  unsigned bits = second ? x1 : x0;
#endif
  float u = __uint_as_float((bits >> 9) | 0x3F800000u) - 1.0f;
  return FMUL(FSUB(u, 0.5f), (float)(2.0 * 3.141592653589793));
}

__device__ __forceinline__ float dot3rn(float ax, float ay, float az,
                                        float bx, float by, float bz) {
  // XLA reduce order over axis of size 3: ((x + y) + z)
  return FADD(FADD(FMUL(ax, bx), FMUL(ay, by)), FMUL(az, bz));
}

// ---------------------------------------------------------------------------
// Kernel 0: AoS -> SoA transpose of xyz into workspace (one-time, 393 KB).
// ---------------------------------------------------------------------------
__global__ __launch_bounds__(256)
void soa_kernel(const float* __restrict__ xyz, float* __restrict__ wsf)
{
  const int i = blockIdx.x * 256 + threadIdx.x;   // point id in [0, B*N)
  if (i < BN) {
    wsf[0 * BN + i] = xyz[i * 3 + 0];
    wsf[1 * BN + i] = xyz[i * 3 + 1];
    wsf[2 * BN + i] = xyz[i * 3 + 2];
  }
}

// ---------------------------------------------------------------------------
// One wave = 2 queries. Phase 1: double-buffered register-prefetch scan of
// SoA coords (coalesced dword loads: 12 lines / 64-pt group vs 36 for AoS),
// both centers tested per staged point, ordered first-32 per query into
// wave-private LDS (lgkmcnt only — no global stores in the loop).
// Phase 2 (same wave, no barrier): lanes 0..31 -> query 0, 32..63 -> query 1;
// angles, stable bitonic sort, invariance + quat channels (validated R7/R11).
// ---------------------------------------------------------------------------
__global__ __launch_bounds__(256)
void qgq_fused(const float* __restrict__ xyz,      // (B, N, 3) — emit gathers
               const float* __restrict__ wsf,      // SoA coords — scan
               const float* __restrict__ new_xyz,  // (B, P, 3)
               float* __restrict__ out)            // (B, 34, P, 32)
{
  __shared__ int sIdx[4][2 * Sc];           // 256 B per wave, wave-private

  const int wave = threadIdx.x >> 6;
  const int lane = threadIdx.x & 63;
  const int q0   = blockIdx.x * 8 + wave * 2;   // wave's first query
  const int b    = q0 >> 11;                    // uniform per block (8 | 2048)
  const int p0   = q0 & 2047;

  const float* xb  = xyz + (size_t)b * Nc * 3;
  const float* sxb = wsf + 0 * BN + b * Nc;
  const float* syb = wsf + 1 * BN + b * Nc;
  const float* szb = wsf + 2 * BN + b * Nc;

  const float c0x = new_xyz[((size_t)b * Pc + p0) * 3 + 0];
  const float c0y = new_xyz[((size_t)b * Pc + p0) * 3 + 1];
  const float c0z = new_xyz[((size_t)b * Pc + p0) * 3 + 2];
  const float c1x = new_xyz[((size_t)b * Pc + p0 + 1) * 3 + 0];
  const float c1y = new_xyz[((size_t)b * Pc + p0 + 1) * 3 + 1];
  const float c1z = new_xyz[((size_t)b * Pc + p0 + 1) * 3 + 2];

  int* sw = sIdx[wave];
  const float R2 = (float)(0.2 * 0.2);
  const unsigned long long below = (1ull << lane) - 1ull;

  auto loadw = [&](int basew, float xs[8], float ys[8], float zs[8]) {
    #pragma unroll
    for (int k = 0; k < 8; ++k) {
      const int i = basew + k * 64 + lane;
      xs[k] = sxb[i];
      ys[k] = syb[i];
      zs[k] = szb[i];
    }
  };

  int run0 = 0, run1 = 0;
  auto procw = [&](int basew, const float xs[8], const float ys[8],
                   const float zs[8]) {
    #pragma unroll
    for (int k = 0; k < 8; ++k) {
      const int idx = basew + k * 64 + lane;
      {  // query 0 (index order preserved per query)
        const float dx = FSUB(c0x, xs[k]);
        const float dy = FSUB(c0y, ys[k]);
        const float dz = FSUB(c0z, zs[k]);
        const float d2 = FADD(FADD(FMUL(dx, dx), FMUL(dy, dy)), FMUL(dz, dz));
        const bool m = d2 < R2;
        const unsigned long long mask = __ballot(m);
        if (m) {
          const int pos = run0 + (int)__popcll(mask & below);
          if (pos < Sc) sw[pos] = idx;            // LDS, lgkmcnt only
        }
        run0 += (int)__popcll(mask);              // wave-uniform
      }
      {  // query 1
        const float dx = FSUB(c1x, xs[k]);
        const float dy = FSUB(c1y, ys[k]);
        const float dz = FSUB(c1z, zs[k]);
        const float d2 = FADD(FADD(FMUL(dx, dx), FMUL(dy, dy)), FMUL(dz, dz));
        const bool m = d2 < R2;
        const unsigned long long mask = __ballot(m);
        if (m) {
          const int pos = run1 + (int)__popcll(mask & below);
          if (pos < Sc) sw[Sc + pos] = idx;
        }
        run1 += (int)__popcll(mask);
      }
    }
  };

  float ax[8], ay[8], az[8], bx[8], by[8], bz[8];
  loadw(0, ax, ay, az);                 // prefetch window 0
  #pragma unroll 1
  for (int basew = 0; basew < Nc; basew += 1024) {   // 8 double-window steps
    loadw(basew + 512, bx, by, bz);                  // prefetch next (valid)
    procw(basew, ax, ay, az);
    if (run0 >= Sc && run1 >= Sc) break;
    loadw((basew + 1024) & (Nc - 1), ax, ay, az);    // prefetch (wrap-clamped)
    procw(basew + 512, bx, by, bz);
    if (run0 >= Sc && run1 >= Sc) break;
  }

  // -------- Phase 2: same wave, no barrier (same-wave LDS RAW is ordered
  // by the compiler's lgkmcnt). Lanes 0..31 -> q0, 32..63 -> q0+1.
  const int half = lane >> 5;
  const int hofs = half << 5;
  const int j    = lane & 31;
  const int q    = q0 + half;
  const int p    = q & 2047;

  const int c0c = (run0 > Sc) ? Sc : run0;   // >=1: center itself has d2==0
  const int c1c = (run1 > Sc) ? Sc : run1;
  const int cnt = half ? c1c : c0c;
  const float cx = half ? c1x : c0x;
  const float cy = half ? c1y : c0y;
  const float cz = half ? c1z : c0z;

  const int gi = sw[hofs + ((j < cnt) ? j : 0)];   // pad with 'first'

  const float ptx = xb[gi * 3 + 0];
  const float pty = xb[gi * 3 + 1];
  const float ptz = xb[gi * 3 + 2];
  const float relx = FSUB(ptx, cx);
  const float rely = FSUB(pty, cy);
  const float relz = FSUB(ptz, cz);

  // p1 = normalize(center)  (single normalization; used for vert & sinus & inv)
  const float n1  = __fsqrt_rn(dot3rn(cx, cy, cz, cx, cy, cz));
  const float id1 = FADD(n1, 1e-6f);
  const float p1x = __fdiv_rn(cx, id1);
  const float p1y = __fdiv_rn(cy, id1);
  const float p1z = __fdiv_rn(cz, id1);

  // p2 = normalize(p1) (double normalization inside _project_one)
  const float n2  = __fsqrt_rn(dot3rn(p1x, p1y, p1z, p1x, p1y, p1z));
  const float id2 = FADD(n2, 1e-6f);
  const float p2x = __fdiv_rn(p1x, id2);
  const float p2y = __fdiv_rn(p1y, id2);
  const float p2z = __fdiv_rn(p1z, id2);

  const bool colin = fabsf(p2x) > (float)(1.0 - 0.001);
  const float rxv = colin ? FMUL(-p2y, p2x) : FSUB(1.0f, FMUL(p2x, p2x));
  const float ryv = colin ? FSUB(1.0f, FMUL(p2y, p2y)) : FMUL(-p2x, p2y);
  const float rzv = colin ? FMUL(-p2y, p2z) : FMUL(-p2x, p2z);
  const float nr  = __fsqrt_rn(dot3rn(rxv, ryv, rzv, rxv, ryv, rzv));
  const float idr = FADD(nr, 1e-6f);
  const float refx = __fdiv_rn(rxv, idr);
  const float refy = __fdiv_rn(ryv, idr);
  const float refz = __fdiv_rn(rzv, idr);

  // projs = normalize(rel - (p1.rel)*p1)
  const float sdot = dot3rn(p1x, p1y, p1z, relx, rely, relz);
  const float wx = FSUB(relx, FMUL(sdot, p1x));
  const float wy = FSUB(rely, FMUL(sdot, p1y));
  const float wz = FSUB(relz, FMUL(sdot, p1z));
  const float nw  = __fsqrt_rn(dot3rn(wx, wy, wz, wx, wy, wz));
  const float idw = FADD(nw, 1e-6f);
  const float prx = __fdiv_rn(wx, idw);
  const float pry = __fdiv_rn(wy, idw);
  const float prz = __fdiv_rn(wz, idw);

  const float s2 = dot3rn(prx, pry, prz, prx, pry, prz);

  float angle;
  if (s2 < 1e-12f) {
    const unsigned n = ((unsigned)q << 5) | (unsigned)j;  // flat idx (B,1,P,S)
    angle = jax_rnd_angle(n);
  } else {
    // cross(ref, projs) . p1  and  ref . projs
    const float ccx = FSUB(FMUL(refy, prz), FMUL(refz, pry));
    const float ccy = FSUB(FMUL(refz, prx), FMUL(refx, prz));
    const float ccz = FSUB(FMUL(refx, pry), FMUL(refy, prx));
    const float sinus   = dot3rn(ccx, ccy, ccz, p1x, p1y, p1z);
    const float cosinus = dot3rn(refx, refy, refz, prx, pry, prz);
    angle = atan2f(sinus, cosinus);
  }

  // ---------------- Stable ascending sort of (angle, j) within each half ---
  // Key: total-order float bits (matches XLA: -0 < +0, no NaNs here) || j.
  // All xor masks <= 16, so comparisons never cross the 32-lane half.
  const unsigned ab   = __float_as_uint(angle);
  const unsigned skey = (ab & 0x80000000u) ? ~ab : (ab | 0x80000000u);
  unsigned long long key = ((unsigned long long)skey << 32) | (unsigned)j;

  #pragma unroll
  for (int k = 2; k <= 32; k <<= 1) {
    #pragma unroll
    for (int jj = k >> 1; jj > 0; jj >>= 1) {
      const unsigned long long other = __shfl_xor(key, jj);
      const bool up      = ((j & k) == 0);       // j, not lane (half-local)
      const bool lower   = ((j & jj) == 0);
      const bool takeMin = (lower == up);
      const unsigned long long mn = (key < other) ? key : other;
      const unsigned long long mx = (key < other) ? other : key;
      key = takeMin ? mn : mx;
    }
  }
  const int oj = (int)(key & 31u);   // original slot landing at position j

  // Gather sorted rel via shuffle (source within this half)
  const float sx = __shfl(relx, oj + hofs);
  const float sy = __shfl(rely, oj + hofs);
  const float sz = __shfl(relz, oj + hofs);

  // ---------------- Outputs (2% tolerance: plain f32 math is fine here)
  const float dotr  = sx * sx + sy * sy + sz * sz;
  const float norm2 = sqrtf(dotr + 1e-12f);
  float cosang = (p1x * sx + p1y * sy + p1z * sz) / norm2;
  const float CL = (float)(1.0 - 1e-6);
  cosang = fminf(fmaxf(cosang, -CL), CL);
  const float ainv = acosf(cosang);

  const float dist = sqrtf(dotr);
  const float invd = 1.0f / (dist + 1e-6f);
  const float oxv = sx * invd, oyv = sy * invd, ozv = sz * invd;
  const float theta = (dist / 0.2f) * (float)(3.141592653589793 / 2.0);
  float st, ct;
  sincosf(theta, &st, &ct);
  const float qw = ct, qx = st * oxv, qy = st * oyv, qz = st * ozv;

  const size_t chs   = (size_t)Pc * Sc;
  const size_t baseo = (size_t)b * CHc * chs + (size_t)p * Sc + (size_t)j;

  out[baseo + 0 * chs] = norm2;
  out[baseo + 1 * chs] = ainv;
  // quats: channel = 2 + comp*8 + m ; value at pos s is q_comp[(s+m)%32]
  #pragma unroll
  for (int m = 0; m < 8; ++m) {
    const int src = ((j + m) & 31) + hofs;
    const float vw = __shfl(qw, src);
    const float vx = __shfl(qx, src);
    const float vy = __shfl(qy, src);
    const float vz = __shfl(qz, src);
    out[baseo + (size_t)(2 + 0 * 8 + m) * chs] = vw;
    out[baseo + (size_t)(2 + 1 * 8 + m) * chs] = vx;
    out[baseo + (size_t)(2 + 2 * 8 + m) * chs] = vy;
    out[baseo + (size_t)(2 + 3 * 8 + m) * chs] = vz;
  }
}

extern "C" void kernel_launch(void* const* d_in, const int* in_sizes, int n_in,
                              void* d_out, int out_size, void* d_ws, size_t ws_size,
                              hipStream_t stream) {
  const float* xyz     = (const float*)d_in[0];
  const float* new_xyz = (const float*)d_in[1];
  // d_in[2] (fps_idx) is dead: reference drops the fps column before use.
  float* out = (float*)d_out;
  float* wsf = (float*)d_ws;   // SoA coords: x[BN] | y[BN] | z[BN] (393 KB)

  hipLaunchKernelGGL(soa_kernel, dim3((BN + 255) / 256), dim3(256), 0, stream,
                     xyz, wsf);

  // 2 queries per wave, 4 waves per block -> 1024 blocks (16 waves/CU).
  hipLaunchKernelGGL(qgq_fused, dim3(NQ / 8), dim3(256), 0, stream,
                     xyz, wsf, new_xyz, out);
}

// Round 14
// 83.437 us; speedup vs baseline: 1.0223x; 1.0223x over previous
//
#include <hip/hip_runtime.h>
#include <math.h>

// ============================================================================
// R14 = R11 (fused, wave-private, 2 queries/wave — the 84.5 us passing best)
// with the scan's vmem REQUEST COUNT cut 4x, register-only (no LDS staging;
// R13's LDS write->read round-trip inside a wave produced stale reads).
// Lane L loads 3 contiguous float4 (16B-aligned) = points 4L..4L+3 of a
// 256-pt window. First-32-by-index preserved exactly via 4 ballots/query and
// rank = run + sum_s' popc(mask_s' & below) + (# own hits with s' < s).
// ============================================================================

// Problem constants (fixed by setup_inputs): B=4, N=8192, P=2048, NSAMPLE=32.
constexpr int Bc  = 4;
constexpr int Nc  = 8192;
constexpr int Pc  = 2048;
constexpr int Sc  = 32;
constexpr int CHc = 34;      // 2 invariance + 4*8 quat channels
constexpr int NQ  = Bc * Pc; // 8192 queries

// JAX >= 0.4.36 defaults jax_threefry_partitionable=True (validated in R1).
#define THREEFRY_PARTITIONABLE 1

#define FMUL __fmul_rn
#define FADD __fadd_rn
#define FSUB __fsub_rn

__device__ __forceinline__ unsigned tf_rotl(unsigned x, int r) {
  return (x << r) | (x >> (32 - r));
}

// Threefry-2x32, 20 rounds, key = (0, 42)  [jax.random.key(42)]
__device__ __forceinline__ void threefry2x32_k42(unsigned& x0, unsigned& x1) {
  const unsigned ks0 = 0u, ks1 = 42u, ks2 = 0u ^ 42u ^ 0x1BD11BDAu;
  x0 += ks0; x1 += ks1;
#define TF_ROUND(r) { x0 += x1; x1 = tf_rotl(x1, (r)); x1 ^= x0; }
  TF_ROUND(13) TF_ROUND(15) TF_ROUND(26) TF_ROUND(6)
  x0 += ks1; x1 += ks2 + 1u;
  TF_ROUND(17) TF_ROUND(29) TF_ROUND(16) TF_ROUND(24)
  x0 += ks2; x1 += ks0 + 2u;
  TF_ROUND(13) TF_ROUND(15) TF_ROUND(26) TF_ROUND(6)
  x0 += ks0; x1 += ks1 + 3u;
  TF_ROUND(17) TF_ROUND(29) TF_ROUND(16) TF_ROUND(24)
  x0 += ks1; x1 += ks2 + 4u;
  TF_ROUND(13) TF_ROUND(15) TF_ROUND(26) TF_ROUND(6)
  x0 += ks2; x1 += ks0 + 5u;
#undef TF_ROUND
}

// Bit-exact replica of (jax.random.uniform(key(42), (B,1,P,S)) - 0.5) * 2*pi
// at flat counter n. Total count = B*1*P*S = 262144.
__device__ __forceinline__ float jax_rnd_angle(unsigned n) {
#if THREEFRY_PARTITIONABLE
  unsigned x0 = 0u, x1 = n;          // hi32(n)=0, lo32(n)=n
  threefry2x32_k42(x0, x1);
  unsigned bits = x0 ^ x1;
#else
  const unsigned half = (unsigned)(Bc * Pc * Sc) / 2u;  // 131072
  unsigned x0, x1;
  bool second = (n >= half);
  if (second) { x0 = n - half; x1 = n; } else { x0 = n; x1 = n + half; }
  threefry2x32_k42(x0, x1);
  unsigned bits = second ? x1 : x0;
#endif
  float u = __uint_as_float((bits >> 9) | 0x3F800000u) - 1.0f;
  return FMUL(FSUB(u, 0.5f), (float)(2.0 * 3.141592653589793));
}

__device__ __forceinline__ float dot3rn(float ax, float ay, float az,
                                        float bx, float by, float bz) {
  // XLA reduce order over axis of size 3: ((x + y) + z)
  return FADD(FADD(FMUL(ax, bx), FMUL(ay, by)), FMUL(az, bz));
}

// ---------------------------------------------------------------------------
// One wave = 2 queries. Phase 1: scan in 256-point windows; lane L owns
// points 4L..4L+3 via 3 contiguous float4 loads (register double-buffered,
// no LDS). 4 ballots per query per window; exact index-order rank:
//   pos(4L+s) = run + sum_{s'} popc(m[s'] & below_L) + #{s'<s : own hit}.
// Hit indices go to the wave-private sIdx LDS scratch (scalar writes, read
// back only in phase 2 — the pattern validated in R8/R11/R12).
// Phase 2 (same wave, no barrier): half-lane emit (validated R7/R11).
// ---------------------------------------------------------------------------
__global__ __launch_bounds__(256)
void qgq_fused(const float* __restrict__ xyz,      // (B, N, 3)
               const float* __restrict__ new_xyz,  // (B, P, 3)
               float* __restrict__ out)            // (B, 34, P, 32)
{
  __shared__ int sIdx[4][2 * Sc];           // 256 B per wave, wave-private

  const int wave = threadIdx.x >> 6;
  const int lane = threadIdx.x & 63;
  const int q0   = blockIdx.x * 8 + wave * 2;   // wave's first query
  const int b    = q0 >> 11;                    // uniform per block (8 | 2048)
  const int p0   = q0 & 2047;

  const float*  xb  = xyz + (size_t)b * Nc * 3;
  const float4* xb4 = reinterpret_cast<const float4*>(xb);

  const float c0x = new_xyz[((size_t)b * Pc + p0) * 3 + 0];
  const float c0y = new_xyz[((size_t)b * Pc + p0) * 3 + 1];
  const float c0z = new_xyz[((size_t)b * Pc + p0) * 3 + 2];
  const float c1x = new_xyz[((size_t)b * Pc + p0 + 1) * 3 + 0];
  const float c1y = new_xyz[((size_t)b * Pc + p0 + 1) * 3 + 1];
  const float c1z = new_xyz[((size_t)b * Pc + p0 + 1) * 3 + 2];

  int* sw = sIdx[wave];
  const float R2 = (float)(0.2 * 0.2);
  const unsigned long long below = (1ull << lane) - 1ull;

  // Load one 256-pt window: lane L takes float4 indices (basep*3)/4 + 3L+k,
  // i.e. floats basep*3 + 12L .. +11 = points basep+4L .. basep+4L+3.
  auto loadv = [&](int basep, float4 r[3]) {
    const float4* src = xb4 + ((basep * 3) >> 2) + 3 * lane;
    r[0] = src[0]; r[1] = src[1]; r[2] = src[2];
  };

  int run0 = 0, run1 = 0;
  auto procw = [&](int basep, const float4 r[3]) {
    // Extract lane-local points s=0..3 (float 3s+c of the 12-float block).
    float px[4], py[4], pz[4];
    px[0] = r[0].x; py[0] = r[0].y; pz[0] = r[0].z;
    px[1] = r[0].w; py[1] = r[1].x; pz[1] = r[1].y;
    px[2] = r[1].z; py[2] = r[1].w; pz[2] = r[2].x;
    px[3] = r[2].y; py[3] = r[2].z; pz[3] = r[2].w;
    const int pbase = basep + 4 * lane;

    {  // query 0
      bool h[4]; unsigned long long m[4];
      #pragma unroll
      for (int s = 0; s < 4; ++s) {
        const float dx = FSUB(c0x, px[s]);
        const float dy = FSUB(c0y, py[s]);
        const float dz = FSUB(c0z, pz[s]);
        const float d2 = FADD(FADD(FMUL(dx, dx), FMUL(dy, dy)), FMUL(dz, dz));
        h[s] = d2 < R2;
        m[s] = __ballot(h[s]);
      }
      const int basecnt = (int)__popcll(m[0] & below) + (int)__popcll(m[1] & below)
                        + (int)__popcll(m[2] & below) + (int)__popcll(m[3] & below);
      int own = 0;
      #pragma unroll
      for (int s = 0; s < 4; ++s) {
        if (h[s]) {
          const int pos = run0 + basecnt + own;
          if (pos < Sc) sw[pos] = pbase + s;
        }
        own += h[s] ? 1 : 0;
      }
      run0 += (int)__popcll(m[0]) + (int)__popcll(m[1])
            + (int)__popcll(m[2]) + (int)__popcll(m[3]);   // wave-uniform
    }
    {  // query 1
      bool h[4]; unsigned long long m[4];
      #pragma unroll
      for (int s = 0; s < 4; ++s) {
        const float dx = FSUB(c1x, px[s]);
        const float dy = FSUB(c1y, py[s]);
        const float dz = FSUB(c1z, pz[s]);
        const float d2 = FADD(FADD(FMUL(dx, dx), FMUL(dy, dy)), FMUL(dz, dz));
        h[s] = d2 < R2;
        m[s] = __ballot(h[s]);
      }
      const int basecnt = (int)__popcll(m[0] & below) + (int)__popcll(m[1] & below)
                        + (int)__popcll(m[2] & below) + (int)__popcll(m[3] & below);
      int own = 0;
      #pragma unroll
      for (int s = 0; s < 4; ++s) {
        if (h[s]) {
          const int pos = run1 + basecnt + own;
          if (pos < Sc) sw[Sc + pos] = pbase + s;
        }
        own += h[s] ? 1 : 0;
      }
      run1 += (int)__popcll(m[0]) + (int)__popcll(m[1])
            + (int)__popcll(m[2]) + (int)__popcll(m[3]);
    }
  };

  float4 cur[3], nxt[3];
  loadv(0, cur);                        // prefetch window 0
  #pragma unroll 1
  for (int basep = 0; basep < Nc; basep += 256) {   // up to 32 windows
    loadv((basep + 256) & (Nc - 1), nxt);           // prefetch next (wrapped)
    procw(basep, cur);
    if (run0 >= Sc && run1 >= Sc) break;
    cur[0] = nxt[0]; cur[1] = nxt[1]; cur[2] = nxt[2];
  }

  // -------- Phase 2: same wave, no barrier (same-wave scalar LDS RAW —
  // the pattern validated in R8/R11/R12). Lanes 0..31 -> q0, 32..63 -> q0+1.
  const int half = lane >> 5;
  const int hofs = half << 5;
  const int j    = lane & 31;
  const int q    = q0 + half;
  const int p    = q & 2047;

  const int c0c = (run0 > Sc) ? Sc : run0;   // >=1: center itself has d2==0
  const int c1c = (run1 > Sc) ? Sc : run1;
  const int cnt = half ? c1c : c0c;
  const float cx = half ? c1x : c0x;
  const float cy = half ? c1y : c0y;
  const float cz = half ? c1z : c0z;

  const int gi = sw[hofs + ((j < cnt) ? j : 0)];   // pad with 'first'

  const float ptx = xb[gi * 3 + 0];
  const float pty = xb[gi * 3 + 1];
  const float ptz = xb[gi * 3 + 2];
  const float relx = FSUB(ptx, cx);
  const float rely = FSUB(pty, cy);
  const float relz = FSUB(ptz, cz);

  // p1 = normalize(center)  (single normalization; used for vert & sinus & inv)
  const float n1  = __fsqrt_rn(dot3rn(cx, cy, cz, cx, cy, cz));
  const float id1 = FADD(n1, 1e-6f);
  const float p1x = __fdiv_rn(cx, id1);
  const float p1y = __fdiv_rn(cy, id1);
  const float p1z = __fdiv_rn(cz, id1);

  // p2 = normalize(p1) (double normalization inside _project_one)
  const float n2  = __fsqrt_rn(dot3rn(p1x, p1y, p1z, p1x, p1y, p1z));
  const float id2 = FADD(n2, 1e-6f);
  const float p2x = __fdiv_rn(p1x, id2);
  const float p2y = __fdiv_rn(p1y, id2);
  const float p2z = __fdiv_rn(p1z, id2);

  const bool colin = fabsf(p2x) > (float)(1.0 - 0.001);
  const float rxv = colin ? FMUL(-p2y, p2x) : FSUB(1.0f, FMUL(p2x, p2x));
  const float ryv = colin ? FSUB(1.0f, FMUL(p2y, p2y)) : FMUL(-p2x, p2y);
  const float rzv = colin ? FMUL(-p2y, p2z) : FMUL(-p2x, p2z);
  const float nr  = __fsqrt_rn(dot3rn(rxv, ryv, rzv, rxv, ryv, rzv));
  const float idr = FADD(nr, 1e-6f);
  const float refx = __fdiv_rn(rxv, idr);
  const float refy = __fdiv_rn(ryv, idr);
  const float refz = __fdiv_rn(rzv, idr);

  // projs = normalize(rel - (p1.rel)*p1)
  const float sdot = dot3rn(p1x, p1y, p1z, relx, rely, relz);
  const float wx = FSUB(relx, FMUL(sdot, p1x));
  const float wy = FSUB(rely, FMUL(sdot, p1y));
  const float wz = FSUB(relz, FMUL(sdot, p1z));
  const float nw  = __fsqrt_rn(dot3rn(wx, wy, wz, wx, wy, wz));
  const float idw = FADD(nw, 1e-6f);
  const float prx = __fdiv_rn(wx, idw);
  const float pry = __fdiv_rn(wy, idw);
  const float prz = __fdiv_rn(wz, idw);

  const float s2 = dot3rn(prx, pry, prz, prx, pry, prz);

  float angle;
  if (s2 < 1e-12f) {
    const unsigned n = ((unsigned)q << 5) | (unsigned)j;  // flat idx (B,1,P,S)
    angle = jax_rnd_angle(n);
  } else {
    // cross(ref, projs) . p1  and  ref . projs
    const float ccx = FSUB(FMUL(refy, prz), FMUL(refz, pry));
    const float ccy = FSUB(FMUL(refz, prx), FMUL(refx, prz));
    const float ccz = FSUB(FMUL(refx, pry), FMUL(refy, prx));
    const float sinus   = dot3rn(ccx, ccy, ccz, p1x, p1y, p1z);
    const float cosinus = dot3rn(refx, refy, refz, prx, pry, prz);
    angle = atan2f(sinus, cosinus);
  }

  // ---------------- Stable ascending sort of (angle, j) within each half ---
  // Key: total-order float bits (matches XLA: -0 < +0, no NaNs here) || j.
  // All xor masks <= 16, so comparisons never cross the 32-lane half.
  const unsigned ab   = __float_as_uint(angle);
  const unsigned skey = (ab & 0x80000000u) ? ~ab : (ab | 0x80000000u);
  unsigned long long key = ((unsigned long long)skey << 32) | (unsigned)j;

  #pragma unroll
  for (int k = 2; k <= 32; k <<= 1) {
    #pragma unroll
    for (int jj = k >> 1; jj > 0; jj >>= 1) {
      const unsigned long long other = __shfl_xor(key, jj);
      const bool up      = ((j & k) == 0);       // j, not lane (half-local)
      const bool lower   = ((j & jj) == 0);
      const bool takeMin = (lower == up);
      const unsigned long long mn = (key < other) ? key : other;
      const unsigned long long mx = (key < other) ? other : key;
      key = takeMin ? mn : mx;
    }
  }
  const int oj = (int)(key & 31u);   // original slot landing at position j

  // Gather sorted rel via shuffle (source within this half)
  const float sx = __shfl(relx, oj + hofs);
  const float sy = __shfl(rely, oj + hofs);
  const float sz = __shfl(relz, oj + hofs);

  // ---------------- Outputs (2% tolerance: plain f32 math is fine here)
  const float dotr  = sx * sx + sy * sy + sz * sz;
  const float norm2 = sqrtf(dotr + 1e-12f);
  float cosang = (p1x * sx + p1y * sy + p1z * sz) / norm2;
  const float CL = (float)(1.0 - 1e-6);
  cosang = fminf(fmaxf(cosang, -CL), CL);
  const float ainv = acosf(cosang);

  const float dist = sqrtf(dotr);
  const float invd = 1.0f / (dist + 1e-6f);
  const float oxv = sx * invd, oyv = sy * invd, ozv = sz * invd;
  const float theta = (dist / 0.2f) * (float)(3.141592653589793 / 2.0);
  float st, ct;
  sincosf(theta, &st, &ct);
  const float qw = ct, qx = st * oxv, qy = st * oyv, qz = st * ozv;

  const size_t chs   = (size_t)Pc * Sc;
  const size_t baseo = (size_t)b * CHc * chs + (size_t)p * Sc + (size_t)j;

  out[baseo + 0 * chs] = norm2;
  out[baseo + 1 * chs] = ainv;
  // quats: channel = 2 + comp*8 + m ; value at pos s is q_comp[(s+m)%32]
  #pragma unroll
  for (int m = 0; m < 8; ++m) {
    const int src = ((j + m) & 31) + hofs;
    const float vw = __shfl(qw, src);
    const float vx = __shfl(qx, src);
    const float vy = __shfl(qy, src);
    const float vz = __shfl(qz, src);
    out[baseo + (size_t)(2 + 0 * 8 + m) * chs] = vw;
    out[baseo + (size_t)(2 + 1 * 8 + m) * chs] = vx;
    out[baseo + (size_t)(2 + 2 * 8 + m) * chs] = vy;
    out[baseo + (size_t)(2 + 3 * 8 + m) * chs] = vz;
  }
}

extern "C" void kernel_launch(void* const* d_in, const int* in_sizes, int n_in,
                              void* d_out, int out_size, void* d_ws, size_t ws_size,
                              hipStream_t stream) {
  const float* xyz     = (const float*)d_in[0];
  const float* new_xyz = (const float*)d_in[1];
  // d_in[2] (fps_idx) is dead: reference drops the fps column before use.
  float* out = (float*)d_out;
  // d_ws unused: single fused kernel, everything stays in registers/LDS.

  // 2 queries per wave, 4 waves per block -> 1024 blocks (16 waves/CU).
  hipLaunchKernelGGL(qgq_fused, dim3(NQ / 8), dim3(256), 0, stream,
                     xyz, new_xyz, out);
}